// Round 1
// baseline (479.973 us; speedup 1.0000x reference)
//
#include <hip/hip_runtime.h>
#include <math.h>

#define BB 2
#define CC 192
#define NH 4
#define CH 48
#define HH 256
#define WW 256
#define NPIX (HH*WW)

typedef __attribute__((ext_vector_type(8))) short short8;   // 8 bf16 = 4 VGPR
typedef __attribute__((ext_vector_type(4))) float f4;

static __device__ __forceinline__ unsigned short f2bf(float f) {
    union { float f; unsigned int u; } c; c.f = f;
    unsigned int r = c.u + 0x7fffu + ((c.u >> 16) & 1u);
    return (unsigned short)(r >> 16);
}

// pack 2 f32 -> 2 bf16 (RTNE, same rounding as f2bf) in one instruction
static __device__ __forceinline__ unsigned int cvtpk_bf16(float lo, float hi) {
    unsigned int r;
    asm("v_cvt_pk_bf16_f32 %0, %1, %2" : "=v"(r) : "v"(lo), "v"(hi));
    return r;
}

// K1: depthwise 3x3 conv for one (b, head, row).
// Restructured: 4 waves x 12 tasks; each task = (type, input-channel g) -> 3 out
// channels over the FULL 256-px row (4 px/lane, float4 loads, shfl halo).
// Row base + weights are wave-uniform (readfirstlane) -> SGPR addressing +
// s_load weights. Next task's rows prefetched (register double-buffer).
// q,k,v all land in LDS [type][ch][132-dword] rows (bf16 px pairs); sumsq for
// q,k is fused in-task (shfl_xor reduce + atomics). After one barrier: v is
// transposed out of LDS to global [n][dg] with 16B stores, then S += q k^T via
// MFMA 16x16x32 bf16 (9 tiles over 4 waves) accumulated to global S atomics.
__global__ __launch_bounds__(256, 2) void k_conv(
    const float* __restrict__ x, const float* __restrict__ wqkv,
    unsigned short* __restrict__ vws, float* __restrict__ Sws,
    float* __restrict__ sqws)
{
    __shared__ unsigned int qkv[3][CH][132];   // 76032 B; 528B row: 16B-aligned

    const int tid  = threadIdx.x;
    const int lane = tid & 63;
    const int wv   = tid >> 6;
    const int hd = blockIdx.x;
    const int y  = blockIdx.y;
    const int b  = blockIdx.z;

    const int y0 = (y > 0) ? (y-1) : 0;
    const int y2 = (y < HH-1) ? (y+1) : y;
    const float my0 = (y > 0) ? 1.f : 0.f;
    const float my2 = (y < HH-1) ? 1.f : 0.f;

    // ---- task loop: t = wv + 4*i, i = 0..11 (each wave: 4 q, 4 k, 4 v tasks)
    int t = __builtin_amdgcn_readfirstlane(wv);
    float4 c0, c1, c2;
    {
        const int type = t >> 4, g = t & 15;
        const float* base = x + ((size_t)(b*CC + type*64 + hd*16 + g))*NPIX;
        c0 = *(const float4*)(base + (size_t)y0*WW + 4*lane);
        c1 = *(const float4*)(base + (size_t)y *WW + 4*lane);
        c2 = *(const float4*)(base + (size_t)y2*WW + 4*lane);
        c0.x *= my0; c0.y *= my0; c0.z *= my0; c0.w *= my0;
        c2.x *= my2; c2.y *= my2; c2.z *= my2; c2.w *= my2;
    }
    for (int i = 0; i < 12; ++i) {
        const int ii = (i < 11) ? (i + 1) : 11;        // last iter: reload self (harmless)
        const int tn = __builtin_amdgcn_readfirstlane(wv + 4*ii);
        float4 n0, n1, n2;
        {
            const int type = tn >> 4, g = tn & 15;
            const float* base = x + ((size_t)(b*CC + type*64 + hd*16 + g))*NPIX;
            n0 = *(const float4*)(base + (size_t)y0*WW + 4*lane);
            n1 = *(const float4*)(base + (size_t)y *WW + 4*lane);
            n2 = *(const float4*)(base + (size_t)y2*WW + 4*lane);
            n0.x *= my0; n0.y *= my0; n0.z *= my0; n0.w *= my0;
            n2.x *= my2; n2.y *= my2; n2.z *= my2; n2.w *= my2;
        }

        const int type = t >> 4, g = t & 15;
        const float* wp = wqkv + type*(CC*9) + hd*(CH*9) + g*27;   // uniform -> s_load
        float w[27];
        #pragma unroll
        for (int j = 0; j < 27; ++j) w[j] = wp[j];

        float a0[4] = {0.f,0.f,0.f,0.f};
        float a1[4] = {0.f,0.f,0.f,0.f};
        float a2[4] = {0.f,0.f,0.f,0.f};
        #pragma unroll
        for (int j = 0; j < 3; ++j) {
            const float4 rr = (j == 0) ? c0 : ((j == 1) ? c1 : c2);
            float lft = __shfl_up(rr.w, 1);   lft = (lane == 0)  ? 0.f : lft;
            float rgt = __shfl_down(rr.x, 1); rgt = (lane == 63) ? 0.f : rgt;
            const float t0[4] = {lft,  rr.x, rr.y, rr.z};
            const float t1[4] = {rr.x, rr.y, rr.z, rr.w};
            const float t2[4] = {rr.y, rr.z, rr.w, rgt };
            #pragma unroll
            for (int p = 0; p < 4; ++p) {
                a0[p] = fmaf(w[   3*j], t0[p], fmaf(w[   3*j+1], t1[p], fmaf(w[   3*j+2], t2[p], a0[p])));
                a1[p] = fmaf(w[ 9+3*j], t0[p], fmaf(w[ 9+3*j+1], t1[p], fmaf(w[ 9+3*j+2], t2[p], a1[p])));
                a2[p] = fmaf(w[18+3*j], t0[p], fmaf(w[18+3*j+1], t1[p], fmaf(w[18+3*j+2], t2[p], a2[p])));
            }
        }

        // fused sum-of-squares for q,k (f32, pre-rounding)
        if (type < 2) {
            float s0 = 0.f, s1 = 0.f, s2 = 0.f;
            #pragma unroll
            for (int p = 0; p < 4; ++p) {
                s0 = fmaf(a0[p], a0[p], s0);
                s1 = fmaf(a1[p], a1[p], s1);
                s2 = fmaf(a2[p], a2[p], s2);
            }
            #pragma unroll
            for (int off = 32; off; off >>= 1) {
                s0 += __shfl_xor(s0, off);
                s1 += __shfl_xor(s1, off);
                s2 += __shfl_xor(s2, off);
            }
            if (lane == 0) {
                float* sq = sqws + ((b*NH + hd)*2 + type)*CH + 3*g;
                atomicAdd(sq + 0, s0); atomicAdd(sq + 1, s1); atomicAdd(sq + 2, s2);
            }
        }

        // pack px pairs to bf16 and write channel rows (contiguous b64, no conflicts)
        {
            uint2 d;
            d.x = cvtpk_bf16(a0[0], a0[1]); d.y = cvtpk_bf16(a0[2], a0[3]);
            ((uint2*)&qkv[type][3*g + 0][0])[lane] = d;
            d.x = cvtpk_bf16(a1[0], a1[1]); d.y = cvtpk_bf16(a1[2], a1[3]);
            ((uint2*)&qkv[type][3*g + 1][0])[lane] = d;
            d.x = cvtpk_bf16(a2[0], a2[1]); d.y = cvtpk_bf16(a2[2], a2[3]);
            ((uint2*)&qkv[type][3*g + 2][0])[lane] = d;
        }

        t = tn; c0 = n0; c1 = n1; c2 = n2;
    }
    __syncthreads();

    // ---- v: transpose out of LDS -> global [n][dg], 6 x 16B stores per pixel
    {
        const unsigned short* vrow = (const unsigned short*)&qkv[2][0][0];
        unsigned short* vp = vws + ((size_t)b*NPIX + (size_t)y*WW + tid)*CC + hd*CH;
        unsigned int d[24];
        #pragma unroll
        for (int c2 = 0; c2 < 24; ++c2) {
            unsigned int lo = vrow[(2*c2    )*264 + tid];   // 132 dwords = 264 shorts/row
            unsigned int hi = vrow[(2*c2 + 1)*264 + tid];
            d[c2] = lo | (hi << 16);
        }
        #pragma unroll
        for (int st = 0; st < 6; ++st) {
            uint4 u; u.x = d[4*st+0]; u.y = d[4*st+1]; u.z = d[4*st+2]; u.w = d[4*st+3];
            *(uint4*)(vp + st*8) = u;
        }
    }

    // ---- S = q k^T via MFMA (unchanged structure)
    {
        const int m = lane & 15, quad = lane >> 4;
        for (int p = wv; p < 9; p += 4) {
            const int ct = p / 3, dt = p - ct*3;
            f4 acc = {0.f, 0.f, 0.f, 0.f};
            const char* qbase = (const char*)&qkv[0][ct*16 + m][0] + quad*16;
            const char* kbase = (const char*)&qkv[1][dt*16 + m][0] + quad*16;
            #pragma unroll
            for (int ks = 0; ks < 8; ++ks) {
                short8 afr = *(const short8*)(qbase + ks*64);
                short8 bfr = *(const short8*)(kbase + ks*64);
                acc = __builtin_amdgcn_mfma_f32_16x16x32_bf16(afr, bfr, acc, 0, 0, 0);
            }
            const int c0i = ct*16 + quad*4, dd = dt*16 + m;
            float* Sp = Sws + ((size_t)(b*NH + hd)*CH + c0i)*CH + dd;
            #pragma unroll
            for (int r = 0; r < 4; ++r) atomicAdd(Sp + r*CH, acc[r]);
        }
    }
}

// K2: one block per (b,head): norms -> logits -> softmax -> W2 = wproj*attn,
// exported bf16 in [o][dg] (A-operand-ready) layout.
__global__ __launch_bounds__(256) void k_attn(
    const float* __restrict__ Sws, const float* __restrict__ sqws,
    const float* __restrict__ temp, const float* __restrict__ wproj,
    unsigned short* __restrict__ W2bf)
{
    __shared__ float att[CH][CH+1];
    __shared__ float wp[CC][CH+1];
    __shared__ float nrm[2][CH];

    const int tid = threadIdx.x;
    const int b  = blockIdx.x >> 2;
    const int hd = blockIdx.x & 3;

    if (tid < 2*CH) {
        int which = tid / CH, cl = tid - which*CH;
        nrm[which][cl] = fmaxf(sqrtf(sqws[((b*NH + hd)*2 + which)*CH + cl]), 1e-12f);
    }
    __syncthreads();

    const float tscale = temp[hd];
    for (int m = tid; m < CH*CH; m += 256) {
        int c = m / CH, d = m - c*CH;
        att[c][d] = Sws[((size_t)(b*NH + hd)*CH + c)*CH + d] * tscale
                    / (nrm[0][c] * nrm[1][d]);
    }
    __syncthreads();

    if (tid < CH) {
        float mx = -1e30f;
        for (int d = 0; d < CH; ++d) mx = fmaxf(mx, att[tid][d]);
        float sm = 0.f;
        for (int d = 0; d < CH; ++d) { float e = expf(att[tid][d] - mx); att[tid][d] = e; sm += e; }
        float inv = 1.f / sm;
        for (int d = 0; d < CH; ++d) att[tid][d] *= inv;
    }

    for (int m = tid; m < CC*CH; m += 256) {
        int o = m / CH, il = m - o*CH;
        wp[o][il] = wproj[o*CC + hd*CH + il];
    }
    __syncthreads();

    const int o0  = (tid & 31) * 6;
    const int dl0 = (tid >> 5) * 6;
    float a[6][6];
    #pragma unroll
    for (int i = 0; i < 6; ++i)
        #pragma unroll
        for (int j = 0; j < 6; ++j) a[i][j] = 0.f;
    for (int il = 0; il < CH; ++il) {
        float wv[6], av[6];
        #pragma unroll
        for (int i = 0; i < 6; ++i) wv[i] = wp[o0+i][il];
        #pragma unroll
        for (int j = 0; j < 6; ++j) av[j] = att[il][dl0+j];
        #pragma unroll
        for (int i = 0; i < 6; ++i)
            #pragma unroll
            for (int j = 0; j < 6; ++j)
                a[i][j] = fmaf(wv[i], av[j], a[i][j]);
    }
    #pragma unroll
    for (int i = 0; i < 6; ++i)
        #pragma unroll
        for (int j = 0; j < 6; ++j)
            W2bf[((size_t)b*CC + o0 + i)*CC + hd*CH + dl0 + j] = f2bf(a[i][j]);
}

// K3: out[b][o][n] = sum_dg W2[o][dg] v[n][dg]  — MFMA GEMM.
// Block: M=192 x N=128, 4 waves in 2x2 (M-half x N-half). A from LDS-staged
// bf16 W2, B straight from global v (16B loads at 64B granularity).
__global__ __launch_bounds__(256, 2) void k_out(
    const unsigned short* __restrict__ vws, const unsigned short* __restrict__ W2bf,
    float* __restrict__ out)
{
    __shared__ unsigned short w2l[CC][200];   // 76800 B; stride 400B: aligned, 2-way banks

    const int tid = threadIdx.x;
    const int b  = blockIdx.y;
    const int n0 = blockIdx.x * 128;

    {
        const uint4* src = (const uint4*)(W2bf + (size_t)b*CC*CC);
        for (int i = tid; i < CC*24; i += 256) {
            int o = i / 24, c = i - o*24;
            *(uint4*)&w2l[o][c*8] = src[i];
        }
    }
    __syncthreads();

    const int lane = tid & 63;
    const int wv = tid >> 6;
    const int m0  = (wv & 1) * 96;
    const int nn0 = (wv >> 1) * 64;
    const int m = lane & 15, quad = lane >> 4;

    f4 acc[6][4];
    #pragma unroll
    for (int mt = 0; mt < 6; ++mt)
        #pragma unroll
        for (int nt = 0; nt < 4; ++nt) acc[mt][nt] = (f4){0.f, 0.f, 0.f, 0.f};

    const unsigned short* vb = vws + ((size_t)b*NPIX + n0 + nn0 + m)*CC + quad*8;

    #pragma unroll
    for (int ks = 0; ks < 6; ++ks) {
        short8 bfr[4];
        #pragma unroll
        for (int nt = 0; nt < 4; ++nt)
            bfr[nt] = *(const short8*)(vb + (size_t)(nt*16)*CC + ks*32);
        short8 afr[6];
        #pragma unroll
        for (int mt = 0; mt < 6; ++mt)
            afr[mt] = *(const short8*)&w2l[m0 + mt*16 + m][ks*32 + quad*8];
        #pragma unroll
        for (int mt = 0; mt < 6; ++mt)
            #pragma unroll
            for (int nt = 0; nt < 4; ++nt)
                acc[mt][nt] = __builtin_amdgcn_mfma_f32_16x16x32_bf16(afr[mt], bfr[nt], acc[mt][nt], 0, 0, 0);
    }

    #pragma unroll
    for (int mt = 0; mt < 6; ++mt) {
        const int o = m0 + mt*16 + quad*4;
        #pragma unroll
        for (int nt = 0; nt < 4; ++nt) {
            const int px = n0 + nn0 + nt*16 + m;
            float* op = out + ((size_t)(b*CC + o))*NPIX + px;
            #pragma unroll
            for (int r = 0; r < 4; ++r) op[(size_t)r*NPIX] = acc[mt][nt][r];
        }
    }
}

extern "C" void kernel_launch(void* const* d_in, const int* in_sizes, int n_in,
                              void* d_out, int out_size, void* d_ws, size_t ws_size,
                              hipStream_t stream)
{
    const float* x     = (const float*)d_in[0];
    const float* wqkv  = (const float*)d_in[1];
    const float* temp  = (const float*)d_in[2];
    const float* wproj = (const float*)d_in[3];
    float* out = (float*)d_out;
    (void)in_sizes; (void)n_in; (void)out_size; (void)ws_size;

    unsigned short* vws = (unsigned short*)d_ws;                 // [b][n][dg] bf16: 50,331,648 B
    const size_t VBYTES = (size_t)BB*CC*NPIX*sizeof(unsigned short);
    float* Sws  = (float*)((char*)d_ws + VBYTES);                // 18432 f
    float* sqws = Sws + (size_t)BB*NH*CH*CH;                     // 768 f
    unsigned short* W2bf = (unsigned short*)(sqws + (size_t)BB*NH*2*CH); // 73728 u16

    hipMemsetAsync(Sws, 0, (size_t)(BB*NH*CH*CH + BB*NH*2*CH)*sizeof(float), stream);
    k_conv<<<dim3(NH, HH, BB), 256, 0, stream>>>(x, wqkv, vws, Sws, sqws);
    k_attn<<<dim3(BB*NH), 256, 0, stream>>>(Sws, sqws, temp, wproj, W2bf);
    k_out<<<dim3(NPIX/128, BB), 256, 0, stream>>>(vws, W2bf, out);
}

// Round 2
// 298.659 us; speedup vs baseline: 1.6071x; 1.6071x over previous
//
#include <hip/hip_runtime.h>
#include <math.h>

#define BB 2
#define CC 192
#define NH 4
#define CH 48
#define SRCP 16
#define HH 256
#define WW 256
#define NPIX (HH*WW)

typedef __attribute__((ext_vector_type(8))) short short8;   // 8 bf16 = 4 VGPR
typedef __attribute__((ext_vector_type(4))) float f4;

static __device__ __forceinline__ unsigned short f2bf(float f) {
    union { float f; unsigned int u; } c; c.f = f;
    unsigned int r = c.u + 0x7fffu + ((c.u >> 16) & 1u);
    return (unsigned short)(r >> 16);
}

// K1: depthwise 3x3 conv for one (b, head, row). q,k -> LDS bf16 rows [c][256]
// (132-dword stride: 16B aligned, 2-way banks = free). v -> global ws in
// [n][dg] layout (bf16, packed dwordx4 stores). Then sumsq(q,k) and
// S += q k^T via MFMA 16x16x32 bf16 (9 tiles x 8 K-steps over 4 waves),
// accumulated to global S with atomics.
// vs round-0: weights read via wave-uniform scalar loads (no wlds staging)
// -> LDS 50688 B -> 3 blocks/CU (was 2). Occupancy is the binding constraint.
__global__ __launch_bounds__(256, 3) void k_conv(
    const float* __restrict__ x, const float* __restrict__ wqkv,
    unsigned short* __restrict__ vws, float* __restrict__ Sws,
    float* __restrict__ sqws)
{
    __shared__ unsigned int qk32[2][CH][132]; // 50688 B -> 3 blocks/CU

    const int tid = threadIdx.x;
    const int hd = blockIdx.x;
    const int y  = blockIdx.y;
    const int b  = blockIdx.z;

    {
        const int xp = tid;
        const int y0 = (y > 0) ? (y-1) : 0;
        const int y2 = (y < HH-1) ? (y+1) : y;
        const int xl = (xp > 0) ? (xp-1) : 0;
        const int xr = (xp < WW-1) ? (xp+1) : xp;
        const float my0 = (y > 0) ? 1.f : 0.f;
        const float my2 = (y < HH-1) ? 1.f : 0.f;
        const float mx0 = (xp > 0) ? 1.f : 0.f;
        const float mx2 = (xp < WW-1) ? 1.f : 0.f;
        const float m00 = my0*mx0, m02 = my0*mx2, m20 = my2*mx0, m22 = my2*mx2;

        // types 0 (q) and 1 (k) -> LDS
        #pragma unroll
        for (int type = 0; type < 2; ++type) {
            const int srcbase = type*64 + SRCP*hd;
            const float* wt = wqkv + type*(CC*9) + hd*(CH*9);   // uniform -> s_load
            for (int g = 0; g < SRCP; ++g) {
                const float* base = x + ((size_t)(b*CC + srcbase + g)*HH)*WW;
                const float* r0 = base + (size_t)y0*WW;
                const float* r1 = base + (size_t)y *WW;
                const float* r2 = base + (size_t)y2*WW;
                float a00 = r0[xl]*m00, a01 = r0[xp]*my0, a02 = r0[xr]*m02;
                float a10 = r1[xl]*mx0, a11 = r1[xp],     a12 = r1[xr]*mx2;
                float a20 = r2[xl]*m20, a21 = r2[xp]*my2, a22 = r2[xr]*m22;
                #pragma unroll
                for (int r = 0; r < 3; ++r) {
                    const int cl = 3*g + r;
                    const float* w = wt + cl*9;
                    float val = a00*w[0] + a01*w[1] + a02*w[2]
                              + a10*w[3] + a11*w[4] + a12*w[5]
                              + a20*w[6] + a21*w[7] + a22*w[8];
                    ((unsigned short*)&qk32[type][cl][0])[xp] = f2bf(val);
                }
            }
        }

        // type 2 (v): fully unrolled so vpack[] stays in registers
        unsigned int vpack[24];
        {
            const int srcbase = 128 + SRCP*hd;
            const float* wt = wqkv + 2*(CC*9) + hd*(CH*9);      // uniform -> s_load
            #pragma unroll
            for (int g = 0; g < SRCP; ++g) {
                const float* base = x + ((size_t)(b*CC + srcbase + g)*HH)*WW;
                const float* r0 = base + (size_t)y0*WW;
                const float* r1 = base + (size_t)y *WW;
                const float* r2 = base + (size_t)y2*WW;
                float a00 = r0[xl]*m00, a01 = r0[xp]*my0, a02 = r0[xr]*m02;
                float a10 = r1[xl]*mx0, a11 = r1[xp],     a12 = r1[xr]*mx2;
                float a20 = r2[xl]*m20, a21 = r2[xp]*my2, a22 = r2[xr]*m22;
                #pragma unroll
                for (int r = 0; r < 3; ++r) {
                    const int cl = 3*g + r;
                    const float* w = wt + cl*9;
                    float val = a00*w[0] + a01*w[1] + a02*w[2]
                              + a10*w[3] + a11*w[4] + a12*w[5]
                              + a20*w[6] + a21*w[7] + a22*w[8];
                    unsigned int u = f2bf(val);
                    if (cl & 1) vpack[cl >> 1] |= (u << 16);
                    else        vpack[cl >> 1]  = u;
                }
            }
        }
        // write v: [b][n][dg] layout, 6 x dwordx4 (16B each, 384B row stride)
        {
            unsigned short* vp = vws + ((size_t)b*NPIX + (size_t)y*WW + xp)*CC + hd*CH;
            #pragma unroll
            for (int st = 0; st < 6; ++st) {
                uint4 u; u.x = vpack[st*4+0]; u.y = vpack[st*4+1];
                         u.z = vpack[st*4+2]; u.w = vpack[st*4+3];
                *(uint4*)(vp + st*8) = u;
            }
        }
    }
    __syncthreads();

    // per-channel sum of squares for q,k norms
    if (tid < 2*CH) {
        const int which = tid / CH;
        const int cl = tid - which*CH;
        const uint4* row = (const uint4*)&qk32[which][cl][0];
        float ssum = 0.f;
        for (int j = 0; j < 32; ++j) {
            uint4 u = row[j];
            #pragma unroll
            for (int q4 = 0; q4 < 4; ++q4) {
                unsigned int w = (&u.x)[q4];
                float lo = __uint_as_float(w << 16);
                float hi = __uint_as_float(w & 0xffff0000u);
                ssum = fmaf(lo, lo, ssum);
                ssum = fmaf(hi, hi, ssum);
            }
        }
        atomicAdd(&sqws[((b*NH + hd)*2 + which)*CH + cl], ssum);
    }

    // S = q k^T via MFMA: A[m=c][k=n], B[k=n][nn=d]; both frags read 8
    // consecutive bf16 from a channel row at n = ks*32 + quad*8.
    {
        const int lane = tid & 63;
        const int wv = tid >> 6;
        const int m = lane & 15, quad = lane >> 4;
        for (int p = wv; p < 9; p += 4) {
            const int ct = p / 3, dt = p - ct*3;
            f4 acc = {0.f, 0.f, 0.f, 0.f};
            const char* qbase = (const char*)&qk32[0][ct*16 + m][0] + quad*16;
            const char* kbase = (const char*)&qk32[1][dt*16 + m][0] + quad*16;
            #pragma unroll
            for (int ks = 0; ks < 8; ++ks) {
                short8 afr = *(const short8*)(qbase + ks*64);
                short8 bfr = *(const short8*)(kbase + ks*64);
                acc = __builtin_amdgcn_mfma_f32_16x16x32_bf16(afr, bfr, acc, 0, 0, 0);
            }
            const int c0 = ct*16 + quad*4, d = dt*16 + m;
            float* Sp = Sws + ((size_t)(b*NH + hd)*CH + c0)*CH + d;
            #pragma unroll
            for (int r = 0; r < 4; ++r) atomicAdd(Sp + r*CH, acc[r]);
        }
    }
}

// K2: one block per (b,head): norms -> logits -> softmax -> W2 = wproj*attn,
// exported bf16 in [o][dg] (A-operand-ready) layout.
__global__ __launch_bounds__(256) void k_attn(
    const float* __restrict__ Sws, const float* __restrict__ sqws,
    const float* __restrict__ temp, const float* __restrict__ wproj,
    unsigned short* __restrict__ W2bf)
{
    __shared__ float att[CH][CH+1];
    __shared__ float wp[CC][CH+1];
    __shared__ float nrm[2][CH];

    const int tid = threadIdx.x;
    const int b  = blockIdx.x >> 2;
    const int hd = blockIdx.x & 3;

    if (tid < 2*CH) {
        int which = tid / CH, cl = tid - which*CH;
        nrm[which][cl] = fmaxf(sqrtf(sqws[((b*NH + hd)*2 + which)*CH + cl]), 1e-12f);
    }
    __syncthreads();

    const float tscale = temp[hd];
    for (int m = tid; m < CH*CH; m += 256) {
        int c = m / CH, d = m - c*CH;
        att[c][d] = Sws[((size_t)(b*NH + hd)*CH + c)*CH + d] * tscale
                    / (nrm[0][c] * nrm[1][d]);
    }
    __syncthreads();

    if (tid < CH) {
        float mx = -1e30f;
        for (int d = 0; d < CH; ++d) mx = fmaxf(mx, att[tid][d]);
        float sm = 0.f;
        for (int d = 0; d < CH; ++d) { float e = expf(att[tid][d] - mx); att[tid][d] = e; sm += e; }
        float inv = 1.f / sm;
        for (int d = 0; d < CH; ++d) att[tid][d] *= inv;
    }

    for (int m = tid; m < CC*CH; m += 256) {
        int o = m / CH, il = m - o*CH;
        wp[o][il] = wproj[o*CC + hd*CH + il];
    }
    __syncthreads();

    const int o0  = (tid & 31) * 6;
    const int dl0 = (tid >> 5) * 6;
    float a[6][6];
    #pragma unroll
    for (int i = 0; i < 6; ++i)
        #pragma unroll
        for (int j = 0; j < 6; ++j) a[i][j] = 0.f;
    for (int il = 0; il < CH; ++il) {
        float wv[6], av[6];
        #pragma unroll
        for (int i = 0; i < 6; ++i) wv[i] = wp[o0+i][il];
        #pragma unroll
        for (int j = 0; j < 6; ++j) av[j] = att[il][dl0+j];
        #pragma unroll
        for (int i = 0; i < 6; ++i)
            #pragma unroll
            for (int j = 0; j < 6; ++j)
                a[i][j] = fmaf(wv[i], av[j], a[i][j]);
    }
    #pragma unroll
    for (int i = 0; i < 6; ++i)
        #pragma unroll
        for (int j = 0; j < 6; ++j)
            W2bf[((size_t)b*CC + o0 + i)*CC + hd*CH + dl0 + j] = f2bf(a[i][j]);
}

// K3: out[b][o][n] = sum_dg W2[o][dg] v[n][dg]  — MFMA GEMM.
// Block: M=192 x N=128, 4 waves in 2x2 (M-half x N-half). A from LDS-staged
// bf16 W2, B straight from global v (16B loads at 64B granularity).
__global__ __launch_bounds__(256, 2) void k_out(
    const unsigned short* __restrict__ vws, const unsigned short* __restrict__ W2bf,
    float* __restrict__ out)
{
    __shared__ unsigned short w2l[CC][200];   // 76800 B; stride 400B: aligned, 2-way banks

    const int tid = threadIdx.x;
    const int b  = blockIdx.y;
    const int n0 = blockIdx.x * 128;

    {
        const uint4* src = (const uint4*)(W2bf + (size_t)b*CC*CC);
        for (int i = tid; i < CC*24; i += 256) {
            int o = i / 24, c = i - o*24;
            *(uint4*)&w2l[o][c*8] = src[i];
        }
    }
    __syncthreads();

    const int lane = tid & 63;
    const int wv = tid >> 6;
    const int m0  = (wv & 1) * 96;
    const int nn0 = (wv >> 1) * 64;
    const int m = lane & 15, quad = lane >> 4;

    f4 acc[6][4];
    #pragma unroll
    for (int mt = 0; mt < 6; ++mt)
        #pragma unroll
        for (int nt = 0; nt < 4; ++nt) acc[mt][nt] = (f4){0.f, 0.f, 0.f, 0.f};

    const unsigned short* vb = vws + ((size_t)b*NPIX + n0 + nn0 + m)*CC + quad*8;

    #pragma unroll
    for (int ks = 0; ks < 6; ++ks) {
        short8 bfr[4];
        #pragma unroll
        for (int nt = 0; nt < 4; ++nt)
            bfr[nt] = *(const short8*)(vb + (size_t)(nt*16)*CC + ks*32);
        short8 afr[6];
        #pragma unroll
        for (int mt = 0; mt < 6; ++mt)
            afr[mt] = *(const short8*)&w2l[m0 + mt*16 + m][ks*32 + quad*8];
        #pragma unroll
        for (int mt = 0; mt < 6; ++mt)
            #pragma unroll
            for (int nt = 0; nt < 4; ++nt)
                acc[mt][nt] = __builtin_amdgcn_mfma_f32_16x16x32_bf16(afr[mt], bfr[nt], acc[mt][nt], 0, 0, 0);
    }

    #pragma unroll
    for (int mt = 0; mt < 6; ++mt) {
        const int o = m0 + mt*16 + quad*4;
        #pragma unroll
        for (int nt = 0; nt < 4; ++nt) {
            const int px = n0 + nn0 + nt*16 + m;
            float* op = out + ((size_t)(b*CC + o))*NPIX + px;
            #pragma unroll
            for (int r = 0; r < 4; ++r) op[(size_t)r*NPIX] = acc[mt][nt][r];
        }
    }
}

extern "C" void kernel_launch(void* const* d_in, const int* in_sizes, int n_in,
                              void* d_out, int out_size, void* d_ws, size_t ws_size,
                              hipStream_t stream)
{
    const float* x     = (const float*)d_in[0];
    const float* wqkv  = (const float*)d_in[1];
    const float* temp  = (const float*)d_in[2];
    const float* wproj = (const float*)d_in[3];
    float* out = (float*)d_out;
    (void)in_sizes; (void)n_in; (void)out_size; (void)ws_size;

    unsigned short* vws = (unsigned short*)d_ws;                 // [b][n][dg] bf16: 50,331,648 B
    const size_t VBYTES = (size_t)BB*CC*NPIX*sizeof(unsigned short);
    float* Sws  = (float*)((char*)d_ws + VBYTES);                // 18432 f
    float* sqws = Sws + (size_t)BB*NH*CH*CH;                     // 768 f
    unsigned short* W2bf = (unsigned short*)(sqws + (size_t)BB*NH*2*CH); // 73728 u16

    hipMemsetAsync(Sws, 0, (size_t)(BB*NH*CH*CH + BB*NH*2*CH)*sizeof(float), stream);
    k_conv<<<dim3(NH, HH, BB), 256, 0, stream>>>(x, wqkv, vws, Sws, sqws);
    k_attn<<<dim3(BB*NH), 256, 0, stream>>>(Sws, sqws, temp, wproj, W2bf);
    k_out<<<dim3(NPIX/128, BB), 256, 0, stream>>>(vws, W2bf, out);
}